// Round 1
// baseline (918.335 us; speedup 1.0000x reference)
//
#include <hip/hip_runtime.h>

#define NN 100000
#define NE 2400000

__global__ void k_init_deg(float* __restrict__ deg) {
    int i = blockIdx.x * blockDim.x + threadIdx.x;
    if (i < NN) deg[i] = 1.0f;
}

__global__ void k_count_deg(const int* __restrict__ ei, float* __restrict__ deg) {
    int e = blockIdx.x * blockDim.x + threadIdx.x;
    if (e < NE) atomicAdd(&deg[ei[NE + e]], 1.0f);
}

__global__ void k_dinv(float* __restrict__ deg) {
    int i = blockIdx.x * blockDim.x + threadIdx.x;
    if (i < NN) deg[i] = rsqrtf(deg[i]);
}

__global__ void k_l1_transform(const float* __restrict__ x, const float* __restrict__ W,
                               const float* __restrict__ dinv,
                               float* __restrict__ h, float* __restrict__ agg) {
    int t = blockIdx.x * blockDim.x + threadIdx.x;
    if (t >= NN * 32) return;
    int i = t >> 5, f = t & 31;
    float v = x[i * 2 + 0] * W[f] + x[i * 2 + 1] * W[32 + f];
    h[t] = v;
    float di = dinv[i];
    agg[t] = di * di * v;
}

__global__ void k_l2_transform(const float* __restrict__ in, const float* __restrict__ W,
                               const float* __restrict__ dinv,
                               float* __restrict__ h, float* __restrict__ agg) {
    __shared__ float Ws[32 * 32];
    for (int j = threadIdx.x; j < 1024; j += blockDim.x) Ws[j] = W[j];
    __syncthreads();
    int t = blockIdx.x * blockDim.x + threadIdx.x;
    if (t >= NN * 32) return;
    int i = t >> 5, f = t & 31;
    const float* row = in + i * 32;
    float v = 0.f;
#pragma unroll
    for (int k = 0; k < 32; ++k) v += row[k] * Ws[k * 32 + f];
    h[t] = v;
    float di = dinv[i];
    agg[t] = di * di * v;
}

__global__ void k_scatter32(const int* __restrict__ ei, const float* __restrict__ dinv,
                            const float* __restrict__ h, float* __restrict__ agg) {
    int t = blockIdx.x * blockDim.x + threadIdx.x;
    int e = t >> 5;
    if (e >= NE) return;
    int f = t & 31;
    int s = ei[e];
    int d = ei[NE + e];
    float nrm = dinv[s] * dinv[d];
    atomicAdd(&agg[d * 32 + f], nrm * h[s * 32 + f]);
}

__global__ void k_finalize32(const float* __restrict__ in, float* __restrict__ outb,
                             const float* __restrict__ b) {
    int t = blockIdx.x * blockDim.x + threadIdx.x;
    if (t >= NN * 32) return;
    float v = in[t] + b[t & 31];
    outb[t] = v > 0.f ? v : 0.f;
}

__global__ void k_l3_transform(const float* __restrict__ in, const float* __restrict__ W,
                               const float* __restrict__ dinv,
                               float* __restrict__ h, float* __restrict__ agg) {
    int i = blockIdx.x * blockDim.x + threadIdx.x;
    if (i >= NN) return;
    const float4* row = (const float4*)(in + i * 32);
    const float4* w4 = (const float4*)W;
    float v = 0.f;
#pragma unroll
    for (int k = 0; k < 8; ++k) {
        float4 r = row[k], w = w4[k];
        v += r.x * w.x + r.y * w.y + r.z * w.z + r.w * w.w;
    }
    h[i] = v;
    float di = dinv[i];
    agg[i] = di * di * v;
}

__global__ void k_scatter1(const int* __restrict__ ei, const float* __restrict__ dinv,
                           const float* __restrict__ h, float* __restrict__ agg) {
    int e = blockIdx.x * blockDim.x + threadIdx.x;
    if (e >= NE) return;
    int s = ei[e];
    int d = ei[NE + e];
    atomicAdd(&agg[d], dinv[s] * dinv[d] * h[s]);
}

__global__ void k_out(const float* __restrict__ agg, const float* __restrict__ b,
                      float* __restrict__ out) {
    int i = blockIdx.x * blockDim.x + threadIdx.x;
    if (i < NN) out[i] = agg[i] + b[0];
}

extern "C" void kernel_launch(void* const* d_in, const int* in_sizes, int n_in,
                              void* d_out, int out_size, void* d_ws, size_t ws_size,
                              hipStream_t stream) {
    const float* x  = (const float*)d_in[0];
    const int*   ei = (const int*)d_in[1];   // [2, NE] int32
    const float* W1 = (const float*)d_in[2];
    const float* b1 = (const float*)d_in[3];
    const float* W2 = (const float*)d_in[4];
    const float* b2 = (const float*)d_in[5];
    const float* W3 = (const float*)d_in[6];
    const float* b3 = (const float*)d_in[7];
    float* out = (float*)d_out;

    float* ws = (float*)d_ws;
    // layout (floats): dinv[0..NN) | X @131072 (32N) | Y @+32N | Z @+32N
    float* dinv = ws;
    float* X = ws + 131072;
    float* Y = X + 32 * NN;
    float* Z = Y + 32 * NN;
    float* h3 = X;            // layer-3 scalars reuse X region
    float* a3 = X + 131072;

    const int B = 256;
    const int G_N   = (NN + B - 1) / B;
    const int G_E   = (NE + B - 1) / B;
    const int G_N32 = (NN * 32 + B - 1) / B;
    const int G_E32 = (NE * 32 + B - 1) / B;

    k_init_deg<<<G_N, B, 0, stream>>>(dinv);
    k_count_deg<<<G_E, B, 0, stream>>>(ei, dinv);
    k_dinv<<<G_N, B, 0, stream>>>(dinv);

    // layer 1: h in X, agg in Y, act -> Y (in-place finalize is safe: elementwise)
    k_l1_transform<<<G_N32, B, 0, stream>>>(x, W1, dinv, X, Y);
    k_scatter32<<<G_E32, B, 0, stream>>>(ei, dinv, X, Y);
    k_finalize32<<<G_N32, B, 0, stream>>>(Y, Y, b1);

    // layer 2: in Y, h in X, agg in Z (no aliasing), act -> Y
    k_l2_transform<<<G_N32, B, 0, stream>>>(Y, W2, dinv, X, Z);
    k_scatter32<<<G_E32, B, 0, stream>>>(ei, dinv, X, Z);
    k_finalize32<<<G_N32, B, 0, stream>>>(Z, Y, b2);

    // layer 3
    k_l3_transform<<<G_N, B, 0, stream>>>(Y, W3, dinv, h3, a3);
    k_scatter1<<<G_E, B, 0, stream>>>(ei, dinv, h3, a3);
    k_out<<<G_N, B, 0, stream>>>(a3, b3, out);
}

// Round 2
// 646.923 us; speedup vs baseline: 1.4195x; 1.4195x over previous
//
#include <hip/hip_runtime.h>

#define NN 100000
#define NE 2400000
#define NBLK 391          // ceil(NN/256)

// ---------------- degree / norm ----------------
__global__ void k_zero_ideg(int* __restrict__ ideg) {
    int i = blockIdx.x * blockDim.x + threadIdx.x;
    if (i < NN) ideg[i] = 0;
}

__global__ void k_count(const int* __restrict__ ei, int* __restrict__ ideg) {
    int e = blockIdx.x * blockDim.x + threadIdx.x;
    if (e < NE) atomicAdd(&ideg[ei[NE + e]], 1);
}

__global__ void k_dinv(const int* __restrict__ ideg, float* __restrict__ dinv) {
    int i = blockIdx.x * blockDim.x + threadIdx.x;
    if (i < NN) dinv[i] = rsqrtf((float)(ideg[i] + 1));  // +1 self-loop
}

// ---------------- exclusive scan (3-phase) ----------------
__global__ void k_scan1(const int* __restrict__ ideg, int* __restrict__ rs,
                        int* __restrict__ bsum) {
    __shared__ int sh[256];
    int tid = threadIdx.x;
    int i = blockIdx.x * 256 + tid;
    int v = (i < NN) ? ideg[i] : 0;
    sh[tid] = v;
    __syncthreads();
    for (int off = 1; off < 256; off <<= 1) {
        int t = (tid >= off) ? sh[tid - off] : 0;
        __syncthreads();
        sh[tid] += t;
        __syncthreads();
    }
    if (i < NN) rs[i] = sh[tid] - v;            // exclusive-in-block
    if (tid == 255) bsum[blockIdx.x] = sh[255]; // block total
}

__global__ void k_scan2(int* __restrict__ bsum, int* __restrict__ boff) {
    __shared__ int sh[512];
    int tid = threadIdx.x;
    int v = (tid < NBLK) ? bsum[tid] : 0;
    sh[tid] = v;
    __syncthreads();
    for (int off = 1; off < 512; off <<= 1) {
        int t = (tid >= off) ? sh[tid - off] : 0;
        __syncthreads();
        sh[tid] += t;
        __syncthreads();
    }
    if (tid < NBLK) boff[tid] = sh[tid] - v;    // exclusive over blocks
}

__global__ void k_scan3(int* __restrict__ rs, const int* __restrict__ boff,
                        int* __restrict__ cursor) {
    int i = blockIdx.x * 256 + threadIdx.x;
    if (i < NN) {
        int r = rs[i] + boff[blockIdx.x];
        rs[i] = r;
        cursor[i] = r;
    }
}

// ---------------- CSR bucket fill ----------------
__global__ void k_bucket(const int* __restrict__ ei, int* __restrict__ cursor,
                         int* __restrict__ csr_src) {
    int e = blockIdx.x * blockDim.x + threadIdx.x;
    if (e >= NE) return;
    int s = ei[e];
    int d = ei[NE + e];
    int pos = atomicAdd(&cursor[d], 1);
    csr_src[pos] = s;
}

// ---------------- layer 1: fused (x@W1) gather + bias + relu ----------------
__global__ void k_gather_l1(const float* __restrict__ x, const int* __restrict__ csr,
                            const int* __restrict__ rs, const int* __restrict__ ideg,
                            const float* __restrict__ dinv, const float* __restrict__ W,
                            const float* __restrict__ b, float* __restrict__ out) {
    int node = blockIdx.x * 8 + (threadIdx.x >> 5);
    int f = threadIdx.x & 31;
    if (node >= NN) return;
    float w0 = W[f], w1 = W[32 + f];
    float di = dinv[node];
    float acc = di * di * (x[node * 2] * w0 + x[node * 2 + 1] * w1);  // self-loop
    int beg = rs[node], cnt = ideg[node];
    for (int e = 0; e < cnt; ++e) {
        int s = csr[beg + e];
        float nrm = di * dinv[s];
        acc += nrm * (x[s * 2] * w0 + x[s * 2 + 1] * w1);
    }
    float v = acc + b[f];
    out[node * 32 + f] = v > 0.f ? v : 0.f;
}

// ---------------- dense 32x32 transform ----------------
__global__ void k_l2_transform(const float* __restrict__ in, const float* __restrict__ W,
                               float* __restrict__ h) {
    __shared__ float Ws[32 * 32];
    for (int j = threadIdx.x; j < 1024; j += blockDim.x) Ws[j] = W[j];
    __syncthreads();
    int t = blockIdx.x * blockDim.x + threadIdx.x;
    if (t >= NN * 32) return;
    int i = t >> 5, f = t & 31;
    const float* row = in + i * 32;
    float v = 0.f;
#pragma unroll
    for (int k = 0; k < 32; ++k) v += row[k] * Ws[k * 32 + f];
    h[t] = v;
}

// ---------------- width-32 gather + bias + relu ----------------
__global__ void k_gather32(const float* __restrict__ h, const int* __restrict__ csr,
                           const int* __restrict__ rs, const int* __restrict__ ideg,
                           const float* __restrict__ dinv, const float* __restrict__ b,
                           float* __restrict__ out) {
    int node = blockIdx.x * 8 + (threadIdx.x >> 5);
    int f = threadIdx.x & 31;
    if (node >= NN) return;
    float di = dinv[node];
    float acc = di * di * h[node * 32 + f];
    int beg = rs[node], cnt = ideg[node];
    for (int e = 0; e < cnt; ++e) {
        int s = csr[beg + e];
        acc += di * dinv[s] * h[s * 32 + f];
    }
    float v = acc + b[f];
    out[node * 32 + f] = v > 0.f ? v : 0.f;
}

// ---------------- layer 3 transform (32 -> 1) ----------------
__global__ void k_l3_transform(const float* __restrict__ in, const float* __restrict__ W,
                               float* __restrict__ h) {
    int i = blockIdx.x * blockDim.x + threadIdx.x;
    if (i >= NN) return;
    const float4* row = (const float4*)(in + i * 32);
    const float4* w4 = (const float4*)W;
    float v = 0.f;
#pragma unroll
    for (int k = 0; k < 8; ++k) {
        float4 r = row[k], w = w4[k];
        v += r.x * w.x + r.y * w.y + r.z * w.z + r.w * w.w;
    }
    h[i] = v;
}

// ---------------- width-1 gather + bias -> output ----------------
__global__ void k_gather_out(const float* __restrict__ h, const int* __restrict__ csr,
                             const int* __restrict__ rs, const int* __restrict__ ideg,
                             const float* __restrict__ dinv, const float* __restrict__ b,
                             float* __restrict__ out) {
    int node = blockIdx.x * blockDim.x + threadIdx.x;
    if (node >= NN) return;
    float di = dinv[node];
    float acc = di * di * h[node];
    int beg = rs[node], cnt = ideg[node];
    for (int e = 0; e < cnt; ++e) {
        int s = csr[beg + e];
        acc += di * dinv[s] * h[s];
    }
    out[node] = acc + b[0];
}

extern "C" void kernel_launch(void* const* d_in, const int* in_sizes, int n_in,
                              void* d_out, int out_size, void* d_ws, size_t ws_size,
                              hipStream_t stream) {
    const float* x  = (const float*)d_in[0];
    const int*   ei = (const int*)d_in[1];   // [2, NE] int32
    const float* W1 = (const float*)d_in[2];
    const float* b1 = (const float*)d_in[3];
    const float* W2 = (const float*)d_in[4];
    const float* b2 = (const float*)d_in[5];
    const float* W3 = (const float*)d_in[6];
    const float* b3 = (const float*)d_in[7];
    float* out = (float*)d_out;

    // workspace layout (4-byte units)
    char* w = (char*)d_ws;
    int*   ideg   = (int*)w;                 w += NN * 4;
    float* dinv   = (float*)w;               w += NN * 4;
    int*   rs     = (int*)w;                 w += NN * 4;
    int*   cursor = (int*)w;                 w += NN * 4;
    int*   bsum   = (int*)w;                 w += 512 * 4;
    int*   boff   = (int*)w;                 w += 512 * 4;
    int*   csr    = (int*)w;                 w += NE * 4;
    float* X      = (float*)w;               w += NN * 32 * 4;   // h buffer
    float* Y      = (float*)w;               w += NN * 32 * 4;   // activations
    float* h3     = (float*)w;               w += NN * 4;

    const int B = 256;
    const int G_N   = (NN + B - 1) / B;        // 391
    const int G_E   = (NE + B - 1) / B;
    const int G_N32 = (NN * 32 + B - 1) / B;
    const int G_G   = (NN + 7) / 8;            // 8 nodes/block for gather32

    // --- build normalization + CSR ---
    k_zero_ideg<<<G_N, B, 0, stream>>>(ideg);
    k_count<<<G_E, B, 0, stream>>>(ei, ideg);
    k_dinv<<<G_N, B, 0, stream>>>(ideg, dinv);
    k_scan1<<<NBLK, 256, 0, stream>>>(ideg, rs, bsum);
    k_scan2<<<1, 512, 0, stream>>>(bsum, boff);
    k_scan3<<<NBLK, 256, 0, stream>>>(rs, boff, cursor);
    k_bucket<<<G_E, B, 0, stream>>>(ei, cursor, csr);

    // --- layer 1 (fused transform+gather) -> Y ---
    k_gather_l1<<<G_G, B, 0, stream>>>(x, csr, rs, ideg, dinv, W1, b1, Y);

    // --- layer 2: Y -> X (h), gather -> Y ---
    k_l2_transform<<<G_N32, B, 0, stream>>>(Y, W2, X);
    k_gather32<<<G_G, B, 0, stream>>>(X, csr, rs, ideg, dinv, b2, Y);

    // --- layer 3: Y -> h3, gather -> out ---
    k_l3_transform<<<G_N, B, 0, stream>>>(Y, W3, h3);
    k_gather_out<<<G_N, B, 0, stream>>>(h3, csr, rs, ideg, dinv, b3, out);
}

// Round 3
// 406.844 us; speedup vs baseline: 2.2572x; 1.5901x over previous
//
#include <hip/hip_runtime.h>

#define NN 100000
#define NE 2400000
#define NB 391              // ceil(NN/256) buckets of 256 dst nodes each

// ---------------- phase 0: zero bucket counters ----------------
__global__ void k_zero(int* __restrict__ cnt) {
    if (threadIdx.x < 512) cnt[threadIdx.x] = 0;
}

// ---------------- phase 1: bucket histogram ----------------
__global__ __launch_bounds__(512) void k_hist(const int* __restrict__ ei,
                                              int* __restrict__ bucketCnt) {
    __shared__ int hist[NB];
    int tid = threadIdx.x;
    for (int i = tid; i < NB; i += 512) hist[i] = 0;
    __syncthreads();
    int e0 = blockIdx.x * 4096;
    for (int k = 0; k < 8; ++k) {
        int e = e0 + k * 512 + tid;
        if (e < NE) atomicAdd(&hist[ei[NE + e] >> 8], 1);
    }
    __syncthreads();
    for (int i = tid; i < NB; i += 512)
        if (hist[i]) atomicAdd(&bucketCnt[i], hist[i]);
}

// ---------------- phase 2: scan buckets ----------------
__global__ __launch_bounds__(512) void k_bucket_scan(const int* __restrict__ bucketCnt,
        int* __restrict__ bucketBase, int* __restrict__ bucketCur, int* __restrict__ rs) {
    __shared__ int sh[512];
    int tid = threadIdx.x;
    int v = (tid < NB) ? bucketCnt[tid] : 0;
    sh[tid] = v; __syncthreads();
    for (int off = 1; off < 512; off <<= 1) {
        int t = (tid >= off) ? sh[tid - off] : 0; __syncthreads();
        sh[tid] += t; __syncthreads();
    }
    int excl = sh[tid] - v;
    if (tid <= NB) bucketBase[tid] = excl;   // bucketBase[NB] = NE (total)
    if (tid < NB) bucketCur[tid] = excl;
    if (tid == 0) rs[NN] = NE;
}

// ---------------- phase 3: bin edges by bucket (LDS-grouped writes) ----------------
__global__ __launch_bounds__(512) void k_binscatter(const int* __restrict__ ei,
        int* __restrict__ bucketCur, int* __restrict__ binned) {
    __shared__ int hist[NB], lbase[NB], myb[NB];
    __shared__ int sh[512];
    __shared__ int stage[4096];
    __shared__ unsigned short stageb[4096];
    __shared__ int tot;
    int tid = threadIdx.x;
    for (int i = tid; i < NB; i += 512) hist[i] = 0;
    __syncthreads();
    int e0 = blockIdx.x * 4096;
    int es[8], ed[8];
    for (int k = 0; k < 8; ++k) {
        int e = e0 + k * 512 + tid;
        if (e < NE) { es[k] = ei[e]; ed[k] = ei[NE + e]; }
        else ed[k] = -1;
    }
    for (int k = 0; k < 8; ++k)
        if (ed[k] >= 0) atomicAdd(&hist[ed[k] >> 8], 1);
    __syncthreads();
    int v = (tid < NB) ? hist[tid] : 0;
    sh[tid] = v; __syncthreads();
    for (int off = 1; off < 512; off <<= 1) {
        int t = (tid >= off) ? sh[tid - off] : 0; __syncthreads();
        sh[tid] += t; __syncthreads();
    }
    if (tid < NB) lbase[tid] = sh[tid] - v;
    if (tid == 511) tot = sh[511];
    if (tid < NB && v > 0) myb[tid] = atomicAdd(&bucketCur[tid], v);
    __syncthreads();
    sh[tid] = 0;                  // reuse as per-bucket rank counters
    __syncthreads();
    for (int k = 0; k < 8; ++k) {
        if (ed[k] >= 0) {
            int b = ed[k] >> 8;
            int r = atomicAdd(&sh[b], 1);
            int slot = lbase[b] + r;
            stage[slot] = es[k] | ((ed[k] & 255) << 17);   // src(17b) | dlow8(8b)
            stageb[slot] = (unsigned short)b;
        }
    }
    __syncthreads();
    int T = tot;
    for (int k = 0; k < 8; ++k) {
        int j = k * 512 + tid;
        if (j < T) {
            int b = stageb[j];
            binned[myb[b] + (j - lbase[b])] = stage[j];    // bucket-grouped runs
        }
    }
}

// ---------------- phase 4: per-bucket local CSR + rs + dinv ----------------
__global__ __launch_bounds__(256) void k_local_csr(const int* __restrict__ binned,
        const int* __restrict__ bucketBase, int* __restrict__ rs,
        float* __restrict__ dinv, int* __restrict__ csr) {
    __shared__ int cnt[256], sh[256], cur[256];
    int tid = threadIdx.x;
    int b = blockIdx.x;
    int e0 = bucketBase[b], e1 = bucketBase[b + 1];
    cnt[tid] = 0;
    __syncthreads();
    for (int j = e0 + tid; j < e1; j += 256)
        atomicAdd(&cnt[(binned[j] >> 17) & 255], 1);
    __syncthreads();
    int v = cnt[tid];
    int node = (b << 8) + tid;
    if (node < NN) dinv[node] = rsqrtf((float)(v + 1));    // +1 self-loop
    sh[tid] = v; __syncthreads();
    for (int off = 1; off < 256; off <<= 1) {
        int t = (tid >= off) ? sh[tid - off] : 0; __syncthreads();
        sh[tid] += t; __syncthreads();
    }
    int excl = sh[tid] - v;
    if (node < NN) rs[node] = e0 + excl;
    cur[tid] = excl;
    __syncthreads();
    for (int j = e0 + tid; j < e1; j += 256) {
        int w = binned[j];
        int ln = (w >> 17) & 255;
        int p = atomicAdd(&cur[ln], 1);
        csr[e0 + p] = w & 0x1FFFF;                         // contiguous region
    }
}

// ---------------- layer 1: fused (x@W1) gather + bias + relu ----------------
__global__ void k_gather_l1(const float* __restrict__ x, const int* __restrict__ csr,
                            const int* __restrict__ rs, const float* __restrict__ dinv,
                            const float* __restrict__ W, const float* __restrict__ b,
                            float* __restrict__ out) {
    int node = blockIdx.x * 8 + (threadIdx.x >> 5);
    int f = threadIdx.x & 31;
    if (node >= NN) return;
    float w0 = W[f], w1 = W[32 + f];
    float di = dinv[node];
    float acc = di * di * (x[node * 2] * w0 + x[node * 2 + 1] * w1);
    int beg = rs[node], end = rs[node + 1];
    for (int e = beg; e < end; ++e) {
        int s = csr[e];
        acc += di * dinv[s] * (x[s * 2] * w0 + x[s * 2 + 1] * w1);
    }
    float vv = acc + b[f];
    out[node * 32 + f] = vv > 0.f ? vv : 0.f;
}

// ---------------- dense 32x32 transform ----------------
__global__ void k_l2_transform(const float* __restrict__ in, const float* __restrict__ W,
                               float* __restrict__ h) {
    __shared__ float Ws[32 * 32];
    for (int j = threadIdx.x; j < 1024; j += blockDim.x) Ws[j] = W[j];
    __syncthreads();
    int t = blockIdx.x * blockDim.x + threadIdx.x;
    if (t >= NN * 32) return;
    int i = t >> 5, f = t & 31;
    const float* row = in + i * 32;
    float v = 0.f;
#pragma unroll
    for (int k = 0; k < 32; ++k) v += row[k] * Ws[k * 32 + f];
    h[t] = v;
}

// ---------------- width-32 gather + bias + relu ----------------
__global__ void k_gather32(const float* __restrict__ h, const int* __restrict__ csr,
                           const int* __restrict__ rs, const float* __restrict__ dinv,
                           const float* __restrict__ b, float* __restrict__ out) {
    int node = blockIdx.x * 8 + (threadIdx.x >> 5);
    int f = threadIdx.x & 31;
    if (node >= NN) return;
    float di = dinv[node];
    float acc = di * di * h[node * 32 + f];
    int beg = rs[node], end = rs[node + 1];
    for (int e = beg; e < end; ++e) {
        int s = csr[e];
        acc += di * dinv[s] * h[s * 32 + f];
    }
    float v = acc + b[f];
    out[node * 32 + f] = v > 0.f ? v : 0.f;
}

// ---------------- layer 3 transform (32 -> 1) ----------------
__global__ void k_l3_transform(const float* __restrict__ in, const float* __restrict__ W,
                               float* __restrict__ h) {
    int i = blockIdx.x * blockDim.x + threadIdx.x;
    if (i >= NN) return;
    const float4* row = (const float4*)(in + i * 32);
    const float4* w4 = (const float4*)W;
    float v = 0.f;
#pragma unroll
    for (int k = 0; k < 8; ++k) {
        float4 r = row[k], w = w4[k];
        v += r.x * w.x + r.y * w.y + r.z * w.z + r.w * w.w;
    }
    h[i] = v;
}

// ---------------- width-1 gather + bias -> output ----------------
__global__ void k_gather_out(const float* __restrict__ h, const int* __restrict__ csr,
                             const int* __restrict__ rs, const float* __restrict__ dinv,
                             const float* __restrict__ b, float* __restrict__ out) {
    int node = blockIdx.x * blockDim.x + threadIdx.x;
    if (node >= NN) return;
    float di = dinv[node];
    float acc = di * di * h[node];
    int beg = rs[node], end = rs[node + 1];
    for (int e = beg; e < end; ++e) {
        int s = csr[e];
        acc += di * dinv[s] * h[s];
    }
    out[node] = acc + b[0];
}

extern "C" void kernel_launch(void* const* d_in, const int* in_sizes, int n_in,
                              void* d_out, int out_size, void* d_ws, size_t ws_size,
                              hipStream_t stream) {
    const float* x  = (const float*)d_in[0];
    const int*   ei = (const int*)d_in[1];   // [2, NE] int32
    const float* W1 = (const float*)d_in[2];
    const float* b1 = (const float*)d_in[3];
    const float* W2 = (const float*)d_in[4];
    const float* b2 = (const float*)d_in[5];
    const float* W3 = (const float*)d_in[6];
    const float* b3 = (const float*)d_in[7];
    float* out = (float*)d_out;

    // workspace layout (4-byte units)
    char* w = (char*)d_ws;
    int*   bucketCnt  = (int*)w;   w += 512 * 4;
    int*   bucketBase = (int*)w;   w += 512 * 4;
    int*   bucketCur  = (int*)w;   w += 512 * 4;
    int*   rs         = (int*)w;   w += (NN + 1) * 4;
    float* dinv       = (float*)w; w += NN * 4;
    int*   csr        = (int*)w;   w += NE * 4;
    float* X          = (float*)w; w += NN * 32 * 4;   // 12.8 MB
    float* Y          = (float*)w; w += NN * 32 * 4;   // 12.8 MB
    int*   binned     = (int*)X;   // 9.6 MB, dead before X is written
    float* h3         = X;         // 400 KB, live only after X is dead

    const int B = 256;
    const int G_N   = (NN + B - 1) / B;        // 391
    const int G_N32 = (NN * 32 + B - 1) / B;   // 12500
    const int G_G   = (NN + 7) / 8;            // 12500
    const int G_BIN = (NE + 4095) / 4096;      // 586

    // --- build CSR (dst-bucketed counting sort) ---
    k_zero<<<1, 512, 0, stream>>>(bucketCnt);
    k_hist<<<G_BIN, 512, 0, stream>>>(ei, bucketCnt);
    k_bucket_scan<<<1, 512, 0, stream>>>(bucketCnt, bucketBase, bucketCur, rs);
    k_binscatter<<<G_BIN, 512, 0, stream>>>(ei, bucketCur, binned);
    k_local_csr<<<NB, 256, 0, stream>>>(binned, bucketBase, rs, dinv, csr);

    // --- layer 1 (fused transform+gather) -> Y ---
    k_gather_l1<<<G_G, B, 0, stream>>>(x, csr, rs, dinv, W1, b1, Y);

    // --- layer 2: Y -> X (h), gather -> Y ---
    k_l2_transform<<<G_N32, B, 0, stream>>>(Y, W2, X);
    k_gather32<<<G_G, B, 0, stream>>>(X, csr, rs, dinv, b2, Y);

    // --- layer 3: Y -> h3, gather -> out ---
    k_l3_transform<<<G_N, B, 0, stream>>>(Y, W3, h3);
    k_gather_out<<<G_N, B, 0, stream>>>(h3, csr, rs, dinv, b3, out);
}